// Round 7
// baseline (2278.316 us; speedup 1.0000x reference)
//
#include <hip/hip_runtime.h>
#include <hip/hip_cooperative_groups.h>
#include <math.h>

namespace cg = cooperative_groups;

#define S_ 257
#define D_ 512
#define MB_ 5  // ceil(257/64)
#define GRID_ 256

struct MegaP {
  const float* in_x;
  const float* emb_w;
  const float* emb_b;
  const float* pos_emb;
  const float* cls_emb;
  const float* ipw;
  const float* ipb;
  const float* aow;
  const float* aob;
  const float* fw1;
  const float* fb1;
  const float* fw2;
  const float* fb2;
  const float* ln1g;
  const float* ln1b;
  const float* ln2g;
  const float* ln2b;
  const float* out_w;
  const float* out_b;
  float* ws;
};

using Tile = float[2][32][68];

// ---- embed row job ---------------------------------------------------------
__device__ __forceinline__ void embed_job(
    int row, const float* __restrict__ in_x, const float* __restrict__ emb_w,
    const float* __restrict__ emb_b, const float* __restrict__ pos_emb,
    const float* __restrict__ cls_emb, float* __restrict__ src,
    float* __restrict__ sbuf) {
  const int tid = threadIdx.x;
  if (row == 0) {
    for (int j = tid; j < D_; j += 256) src[j] = cls_emb[j] + pos_emb[j];
    __syncthreads();
    return;
  }
  if (tid < 64) sbuf[tid] = in_x[(row - 1) * 64 + tid];
  __syncthreads();
  for (int j = tid; j < D_; j += 256) {
    float acc = emb_b[j];
#pragma unroll 8
    for (int k = 0; k < 64; ++k) acc += sbuf[k] * emb_w[k * D_ + j];
    src[row * D_ + j] = acc + pos_emb[row * D_ + j];
  }
  __syncthreads();
}

// ---- proven 64x64 dbuf GEMM datapath as a per-block job --------------------
template <bool TRANSB, bool RELU, bool SPLITK>
__device__ __forceinline__ void gemm_job(
    int job, const float* __restrict__ A, const float* __restrict__ B,
    const float* __restrict__ bias, float* __restrict__ out, int M, int N,
    int K, int kslice, int nb, int MNtot, Tile& As, Tile& Bs) {
  const int tid = threadIdx.x;
  const int by = job % MB_;
  const int t2 = job / MB_;
  const int bx = t2 % nb;
  const int bz = t2 / nb;
  const int m0 = by * 64, n0 = bx * 64, kbeg = bz * kslice;

  const int sm = tid & 63;
  const int sk = (tid >> 6) * 8;
  const int bk = tid >> 3;
  const int bn = (tid & 7) * 8;

  float4 ra0, ra1, rb0, rb1;
  const float4 z4 = make_float4(0.f, 0.f, 0.f, 0.f);

  auto loadT = [&](int k0) {
    const int gm = m0 + sm;
    if (gm < M) {
      const float* p = &A[(size_t)gm * K + k0 + sk];
      ra0 = *reinterpret_cast<const float4*>(p);
      ra1 = *reinterpret_cast<const float4*>(p + 4);
    } else {
      ra0 = z4;
      ra1 = z4;
    }
    if (TRANSB) {
      const float* p = &B[(size_t)(n0 + sm) * K + k0 + sk];
      rb0 = *reinterpret_cast<const float4*>(p);
      rb1 = *reinterpret_cast<const float4*>(p + 4);
    } else {
      const float* p = &B[(size_t)(k0 + bk) * N + n0 + bn];
      rb0 = *reinterpret_cast<const float4*>(p);
      rb1 = *reinterpret_cast<const float4*>(p + 4);
    }
  };
  auto storeT = [&](int b) {
    As[b][sk + 0][sm] = ra0.x;
    As[b][sk + 1][sm] = ra0.y;
    As[b][sk + 2][sm] = ra0.z;
    As[b][sk + 3][sm] = ra0.w;
    As[b][sk + 4][sm] = ra1.x;
    As[b][sk + 5][sm] = ra1.y;
    As[b][sk + 6][sm] = ra1.z;
    As[b][sk + 7][sm] = ra1.w;
    if (TRANSB) {
      Bs[b][sk + 0][sm] = rb0.x;
      Bs[b][sk + 1][sm] = rb0.y;
      Bs[b][sk + 2][sm] = rb0.z;
      Bs[b][sk + 3][sm] = rb0.w;
      Bs[b][sk + 4][sm] = rb1.x;
      Bs[b][sk + 5][sm] = rb1.y;
      Bs[b][sk + 6][sm] = rb1.z;
      Bs[b][sk + 7][sm] = rb1.w;
    } else {
      *reinterpret_cast<float4*>(&Bs[b][bk][bn]) = rb0;
      *reinterpret_cast<float4*>(&Bs[b][bk][bn + 4]) = rb1;
    }
  };

  float acc[4][4] = {};
  const int tx4 = (tid & 15) * 4;
  const int ty4 = (tid >> 4) * 4;

  const int nt = kslice >> 5;
  loadT(kbeg);
  storeT(0);
  __syncthreads();
  int buf = 0;
  for (int t = 0; t < nt; ++t) {
    const bool more = (t + 1 < nt);
    if (more) loadT(kbeg + (t + 1) * 32);
#pragma unroll
    for (int k = 0; k < 32; ++k) {
      const float4 av = *reinterpret_cast<const float4*>(&As[buf][k][ty4]);
      const float4 bv = *reinterpret_cast<const float4*>(&Bs[buf][k][tx4]);
      acc[0][0] += av.x * bv.x;
      acc[0][1] += av.x * bv.y;
      acc[0][2] += av.x * bv.z;
      acc[0][3] += av.x * bv.w;
      acc[1][0] += av.y * bv.x;
      acc[1][1] += av.y * bv.y;
      acc[1][2] += av.y * bv.z;
      acc[1][3] += av.y * bv.w;
      acc[2][0] += av.z * bv.x;
      acc[2][1] += av.z * bv.y;
      acc[2][2] += av.z * bv.z;
      acc[2][3] += av.z * bv.w;
      acc[3][0] += av.w * bv.x;
      acc[3][1] += av.w * bv.y;
      acc[3][2] += av.w * bv.z;
      acc[3][3] += av.w * bv.w;
    }
    if (more) storeT(buf ^ 1);
    __syncthreads();
    buf ^= 1;
  }

  float* pb = SPLITK ? (out + (size_t)bz * MNtot) : out;
#pragma unroll
  for (int i = 0; i < 4; ++i) {
    const int m = m0 + ty4 + i;
    if (m >= M) break;
    const int n = n0 + tx4;
    float4 v = make_float4(acc[i][0], acc[i][1], acc[i][2], acc[i][3]);
    if (!SPLITK) {
      const float4 bb = *reinterpret_cast<const float4*>(&bias[n]);
      v.x += bb.x;
      v.y += bb.y;
      v.z += bb.z;
      v.w += bb.w;
      if (RELU) {
        v.x = fmaxf(v.x, 0.f);
        v.y = fmaxf(v.y, 0.f);
        v.z = fmaxf(v.z, 0.f);
        v.w = fmaxf(v.w, 0.f);
      }
    }
    *reinterpret_cast<float4*>(&pb[(size_t)m * N + n]) = v;
  }
  __syncthreads();
}

// ---- attention job: one query row, 8 head-groups x 32 lanes ----------------
__device__ __forceinline__ void attn_job(int q, const float* __restrict__ qkv,
                                         float* __restrict__ attnO,
                                         float (*sc)[260], float (*qsh)[64]) {
  const int tid = threadIdx.x;
  const int lane = tid & 31;
  const int hg = tid >> 5;
  {
    const int e = tid * 2;
    const float2 v =
        *reinterpret_cast<const float2*>(&qkv[(size_t)q * 1536 + e]);
    qsh[e >> 6][e & 63] = v.x;
    qsh[e >> 6][(e & 63) + 1] = v.y;
  }
  __syncthreads();
  float lm = -1e30f;
  for (int j = lane; j < S_; j += 32) {
    const float4* kr =
        reinterpret_cast<const float4*>(&qkv[(size_t)j * 1536 + 512 + hg * 64]);
    const float4* qr = reinterpret_cast<const float4*>(&qsh[hg][0]);
    float acc = 0.f;
#pragma unroll
    for (int d = 0; d < 16; ++d) {
      const float4 kk = kr[d], qq = qr[d];
      acc += kk.x * qq.x + kk.y * qq.y + kk.z * qq.z + kk.w * qq.w;
    }
    const float s = acc * 0.125f;
    sc[hg][j] = s;
    lm = fmaxf(lm, s);
  }
#pragma unroll
  for (int off = 16; off > 0; off >>= 1)
    lm = fmaxf(lm, __shfl_xor(lm, off, 32));
  float ls = 0.f;
  for (int j = lane; j < S_; j += 32) {
    const float pw = __expf(sc[hg][j] - lm);
    sc[hg][j] = pw;
    ls += pw;
  }
#pragma unroll
  for (int off = 16; off > 0; off >>= 1) ls += __shfl_xor(ls, off, 32);
  const float inv = 1.f / ls;
  __syncthreads();
  float a0 = 0.f, a1 = 0.f;
  for (int j = 0; j < S_; ++j) {
    const float pw = sc[hg][j];
    const float2 vv = *reinterpret_cast<const float2*>(
        &qkv[(size_t)j * 1536 + 1024 + hg * 64 + lane * 2]);
    a0 += pw * vv.x;
    a1 += pw * vv.y;
  }
  *reinterpret_cast<float2*>(&attnO[(size_t)q * D_ + hg * 64 + lane * 2]) =
      make_float2(a0 * inv, a1 * inv);
  __syncthreads();
}

// ---- split-K reduce + bias + residual + LayerNorm row job ------------------
__device__ __forceinline__ void ln_job(int row, const float* __restrict__ part,
                                       int S, const float* __restrict__ bias,
                                       float* __restrict__ io,
                                       const float* __restrict__ g,
                                       const float* __restrict__ b,
                                       float* redA, float* redB) {
  const int tid = threadIdx.x;
  const size_t base = (size_t)row * D_;
  float x0 = io[base + tid] + bias[tid];
  float x1 = io[base + 256 + tid] + bias[256 + tid];
  for (int s = 0; s < S; ++s) {
    x0 += part[(size_t)s * (size_t)(S_ * D_) + base + tid];
    x1 += part[(size_t)s * (size_t)(S_ * D_) + base + 256 + tid];
  }
  float sm = x0 + x1;
#pragma unroll
  for (int off = 32; off > 0; off >>= 1) sm += __shfl_down(sm, off);
  if ((tid & 63) == 0) redA[tid >> 6] = sm;
  __syncthreads();
  const float mu = (redA[0] + redA[1] + redA[2] + redA[3]) * (1.f / 512.f);
  const float d0 = x0 - mu, d1 = x1 - mu;
  float qv = d0 * d0 + d1 * d1;
#pragma unroll
  for (int off = 32; off > 0; off >>= 1) qv += __shfl_down(qv, off);
  if ((tid & 63) == 0) redB[tid >> 6] = qv;
  __syncthreads();
  const float var = (redB[0] + redB[1] + redB[2] + redB[3]) * (1.f / 512.f);
  const float inv = rsqrtf(var + 1e-5f);
  io[base + tid] = d0 * inv * g[tid] + b[tid];
  io[base + 256 + tid] = d1 * inv * g[256 + tid] + b[256 + tid];
  __syncthreads();
}

// ---- head gemv / logits jobs -----------------------------------------------
__device__ __forceinline__ void gemv_job(int job, const float* __restrict__ src,
                                         const float* __restrict__ out_w,
                                         float* __restrict__ part,
                                         float* __restrict__ sbuf) {
  const int tid = threadIdx.x;
  const int jc = job & 63;
  const int dc = job >> 6;
  if (tid < 64) sbuf[tid] = src[dc * 64 + tid];
  __syncthreads();
  const int j0 = jc * 1024 + tid * 4;
  float4 acc = make_float4(0.f, 0.f, 0.f, 0.f);
  for (int d = 0; d < 64; ++d) {
    const float sv = sbuf[d];
    const float4 w = *reinterpret_cast<const float4*>(
        &out_w[(size_t)(dc * 64 + d) * 65536 + j0]);
    acc.x += sv * w.x;
    acc.y += sv * w.y;
    acc.z += sv * w.z;
    acc.w += sv * w.w;
  }
  *reinterpret_cast<float4*>(&part[(size_t)dc * 65536 + j0]) = acc;
  __syncthreads();
}

__device__ __forceinline__ void logits_job(int job,
                                           const float* __restrict__ part,
                                           const float* __restrict__ out_b,
                                           float* __restrict__ logits) {
  const int j = job * 1024 + threadIdx.x * 4;
  float4 acc = *reinterpret_cast<const float4*>(&out_b[j]);
#pragma unroll
  for (int s = 0; s < 8; ++s) {
    const float4 v =
        *reinterpret_cast<const float4*>(&part[(size_t)s * 65536 + j]);
    acc.x += v.x;
    acc.y += v.y;
    acc.z += v.z;
    acc.w += v.w;
  }
  *reinterpret_cast<float4*>(&logits[j]) = acc;
}

// ---- the megakernel --------------------------------------------------------
__global__ __launch_bounds__(256, 2) void mega(MegaP p) {
  cg::grid_group grid = cg::this_grid();
  const int bid = blockIdx.x;

  __shared__ __align__(16) float As[2][32][68];
  __shared__ __align__(16) float Bs[2][32][68];
  __shared__ __align__(16) float sc[8][260];
  __shared__ __align__(16) float qsh[8][64];
  __shared__ float redA[4], redB[4];
  __shared__ __align__(16) float sbuf[64];

  float* ws = p.ws;
  float* src = ws;               // 257*512
  float* qkv = ws + 131584;      // 257*1536
  float* attnO = ws + 526336;    // 257*512
  float* ffh = ws + 657920;      // 257*2048
  float* logits = ws + 1184256;  // 65536
  float* part = ws + 1249792;    // 8*131584 (also 8*65536 head partials)

  for (int row = bid; row < S_; row += GRID_)
    embed_job(row, p.in_x, p.emb_w, p.emb_b, p.pos_emb, p.cls_emb, src, sbuf);
  grid.sync();

  for (int l = 0; l < 4; ++l) {
    const float* ipw_l = p.ipw + (size_t)l * 1536 * 512;
    const float* ipb_l = p.ipb + l * 1536;
    const float* aow_l = p.aow + (size_t)l * 512 * 512;
    const float* aob_l = p.aob + l * 512;
    const float* fw1_l = p.fw1 + (size_t)l * 512 * 2048;
    const float* fb1_l = p.fb1 + l * 2048;
    const float* fw2_l = p.fw2 + (size_t)l * 2048 * 512;
    const float* fb2_l = p.fb2 + l * 512;

    for (int job = bid; job < 24 * MB_; job += GRID_)
      gemm_job<true, false, false>(job, src, ipw_l, ipb_l, qkv, S_, 1536, 512,
                                   512, 24, 0, As, Bs);
    grid.sync();

    for (int q = bid; q < S_; q += GRID_) attn_job(q, qkv, attnO, sc, qsh);
    grid.sync();

    for (int job = bid; job < 8 * MB_ * 8; job += GRID_)
      gemm_job<true, false, true>(job, attnO, aow_l, nullptr, part, S_, 512,
                                  512, 64, 8, S_ * D_, As, Bs);
    grid.sync();

    for (int row = bid; row < S_; row += GRID_)
      ln_job(row, part, 8, aob_l, src, p.ln1g + l * 512, p.ln1b + l * 512,
             redA, redB);
    grid.sync();

    for (int job = bid; job < 32 * MB_; job += GRID_)
      gemm_job<false, true, false>(job, src, fw1_l, fb1_l, ffh, S_, 2048, 512,
                                   512, 32, 0, As, Bs);
    grid.sync();

    for (int job = bid; job < 8 * MB_ * 8; job += GRID_)
      gemm_job<false, false, true>(job, ffh, fw2_l, nullptr, part, S_, 512,
                                   2048, 256, 8, S_ * D_, As, Bs);
    grid.sync();

    for (int row = bid; row < S_; row += GRID_)
      ln_job(row, part, 8, fb2_l, src, p.ln2g + l * 512, p.ln2b + l * 512,
             redA, redB);
    grid.sync();
  }

  for (int job = bid; job < 512; job += GRID_)
    gemv_job(job, src, p.out_w, part, sbuf);
  grid.sync();

  for (int job = bid; job < 64; job += GRID_)
    logits_job(job, part, p.out_b, logits);
}

// ---- fallback wrappers (non-cooperative), reuse the same device jobs -------
__global__ __launch_bounds__(256) void embed_wrap(
    const float* in_x, const float* emb_w, const float* emb_b,
    const float* pos_emb, const float* cls_emb, float* src) {
  __shared__ __align__(16) float sbuf[64];
  embed_job(blockIdx.x, in_x, emb_w, emb_b, pos_emb, cls_emb, src, sbuf);
}

template <bool TRANSB, bool RELU, bool SPLITK>
__global__ __launch_bounds__(256, 2) void gemm_wrap(const float* A,
                                                    const float* B,
                                                    const float* bias,
                                                    float* out, int M, int N,
                                                    int K, int kslice, int nb,
                                                    int MNtot) {
  __shared__ __align__(16) float As[2][32][68];
  __shared__ __align__(16) float Bs[2][32][68];
  gemm_job<TRANSB, RELU, SPLITK>(blockIdx.x, A, B, bias, out, M, N, K, kslice,
                                 nb, MNtot, As, Bs);
}

__global__ __launch_bounds__(256) void attn_wrap(const float* qkv,
                                                 float* attnO) {
  __shared__ __align__(16) float sc[8][260];
  __shared__ __align__(16) float qsh[8][64];
  attn_job(blockIdx.x, qkv, attnO, sc, qsh);
}

__global__ __launch_bounds__(256) void ln_wrap(const float* part, int S,
                                               const float* bias, float* io,
                                               const float* g, const float* b) {
  __shared__ float redA[4], redB[4];
  ln_job(blockIdx.x, part, S, bias, io, g, b, redA, redB);
}

__global__ __launch_bounds__(256) void gemv_wrap(const float* src,
                                                 const float* out_w,
                                                 float* part) {
  __shared__ __align__(16) float sbuf[64];
  gemv_job(blockIdx.x, src, out_w, part, sbuf);
}

__global__ __launch_bounds__(256) void logits_wrap(const float* part,
                                                   const float* out_b,
                                                   float* logits) {
  logits_job(blockIdx.x, part, out_b, logits);
}

// ---------------- sinkhorn (rank-1 reformulation, unchanged) ----------------
__global__ __launch_bounds__(1024) void sinkhorn_kernel(
    const float* __restrict__ logits, float* __restrict__ out) {
  const int tid = threadIdx.x;
  const int tx = tid & 31;
  const int ty = tid >> 5;
  const int i0 = ty * 8, j0 = tx * 8;
  float E[8][8];
#pragma unroll
  for (int ii = 0; ii < 8; ++ii) {
    const float4 a =
        *reinterpret_cast<const float4*>(&logits[(i0 + ii) * 256 + j0]);
    const float4 b =
        *reinterpret_cast<const float4*>(&logits[(i0 + ii) * 256 + j0 + 4]);
    E[ii][0] = __expf(a.x);
    E[ii][1] = __expf(a.y);
    E[ii][2] = __expf(a.z);
    E[ii][3] = __expf(a.w);
    E[ii][4] = __expf(b.x);
    E[ii][5] = __expf(b.y);
    E[ii][6] = __expf(b.z);
    E[ii][7] = __expf(b.w);
  }
  __shared__ float part[32][8][32];
  __shared__ int partI[32][8][32];
  __shared__ float uu[256];
  __shared__ float vv[256];
  __shared__ int amax[256];
  if (tid < 256) uu[tid] = 1.f;
  __syncthreads();
  for (int it = 0; it < 20; ++it) {
    float ul[8];
#pragma unroll
    for (int ii = 0; ii < 8; ++ii) ul[ii] = uu[i0 + ii];
#pragma unroll
    for (int jj = 0; jj < 8; ++jj) {
      float s = 0.f;
#pragma unroll
      for (int ii = 0; ii < 8; ++ii) s += E[ii][jj] * ul[ii];
      part[ty][jj][tx] = s;
    }
    __syncthreads();
    if (tid < 256) {
      const int jj = tid >> 5, txr = tid & 31;
      float s = 0.f;
#pragma unroll
      for (int p = 0; p < 32; ++p) s += part[p][jj][txr];
      vv[txr * 8 + jj] = 1.f / s;
    }
    __syncthreads();
    float vl[8];
#pragma unroll
    for (int jj = 0; jj < 8; ++jj) vl[jj] = vv[j0 + jj];
#pragma unroll
    for (int ii = 0; ii < 8; ++ii) {
      float s = 0.f;
#pragma unroll
      for (int jj = 0; jj < 8; ++jj) s += E[ii][jj] * vl[jj];
      part[ty][ii][tx] = s;
    }
    __syncthreads();
    if (tid < 256) {
      const int i = tid;
      float s = 0.f;
#pragma unroll
      for (int p = 0; p < 32; ++p) {
        const int pr = (p + i) & 31;
        s += part[i >> 3][i & 7][pr];
      }
      uu[i] = 1.f / s;
    }
    __syncthreads();
  }
  float ul[8], vl[8];
#pragma unroll
  for (int ii = 0; ii < 8; ++ii) ul[ii] = uu[i0 + ii];
#pragma unroll
  for (int jj = 0; jj < 8; ++jj) vl[jj] = vv[j0 + jj];
#pragma unroll
  for (int ii = 0; ii < 8; ++ii) {
    float vals[8];
    float best = -1.f;
    int bidx = 0;
#pragma unroll
    for (int jj = 0; jj < 8; ++jj) {
      const float p = E[ii][jj] * ul[ii] * vl[jj];
      vals[jj] = p;
      if (p > best) {
        best = p;
        bidx = j0 + jj;
      }
    }
    *reinterpret_cast<float4*>(&out[(i0 + ii) * 256 + j0]) =
        make_float4(vals[0], vals[1], vals[2], vals[3]);
    *reinterpret_cast<float4*>(&out[(i0 + ii) * 256 + j0 + 4]) =
        make_float4(vals[4], vals[5], vals[6], vals[7]);
    part[ty][ii][tx] = best;
    partI[ty][ii][tx] = bidx;
  }
  __syncthreads();
  if (tid < 256) {
    const int i = tid;
    float best = -1.f;
    int bidx = 1 << 30;
#pragma unroll
    for (int p = 0; p < 32; ++p) {
      const int pr = (p + i) & 31;
      const float v = part[i >> 3][i & 7][pr];
      const int ix = partI[i >> 3][i & 7][pr];
      if (v > best || (v == best && ix < bidx)) {
        best = v;
        bidx = ix;
      }
    }
    amax[i] = bidx;
  }
  __syncthreads();
#pragma unroll
  for (int ii = 0; ii < 8; ++ii) {
    const int am = amax[i0 + ii];
    float4 h0, h1;
    h0.x = (j0 + 0 == am) ? 1.f : 0.f;
    h0.y = (j0 + 1 == am) ? 1.f : 0.f;
    h0.z = (j0 + 2 == am) ? 1.f : 0.f;
    h0.w = (j0 + 3 == am) ? 1.f : 0.f;
    h1.x = (j0 + 4 == am) ? 1.f : 0.f;
    h1.y = (j0 + 5 == am) ? 1.f : 0.f;
    h1.z = (j0 + 6 == am) ? 1.f : 0.f;
    h1.w = (j0 + 7 == am) ? 1.f : 0.f;
    *reinterpret_cast<float4*>(&out[65536 + (i0 + ii) * 256 + j0]) = h0;
    *reinterpret_cast<float4*>(&out[65536 + (i0 + ii) * 256 + j0 + 4]) = h1;
  }
}

// ---------------- host-side launch ------------------------------------------
extern "C" void kernel_launch(void* const* d_in, const int* in_sizes, int n_in,
                              void* d_out, int out_size, void* d_ws,
                              size_t ws_size, hipStream_t stream) {
  (void)in_sizes;
  (void)n_in;
  (void)out_size;
  (void)ws_size;
  MegaP p;
  p.in_x = (const float*)d_in[0];
  p.emb_w = (const float*)d_in[1];
  p.emb_b = (const float*)d_in[2];
  p.pos_emb = (const float*)d_in[3];
  p.cls_emb = (const float*)d_in[4];
  p.ipw = (const float*)d_in[5];
  p.ipb = (const float*)d_in[6];
  p.aow = (const float*)d_in[7];
  p.aob = (const float*)d_in[8];
  p.fw1 = (const float*)d_in[9];
  p.fb1 = (const float*)d_in[10];
  p.fw2 = (const float*)d_in[11];
  p.fb2 = (const float*)d_in[12];
  p.ln1g = (const float*)d_in[13];
  p.ln1b = (const float*)d_in[14];
  p.ln2g = (const float*)d_in[15];
  p.ln2b = (const float*)d_in[16];
  p.out_w = (const float*)d_in[17];
  p.out_b = (const float*)d_in[18];
  p.ws = (float*)d_ws;
  float* out = (float*)d_out;
  float* ws = p.ws;
  float* src = ws;
  float* qkv = ws + 131584;
  float* attnO = ws + 526336;
  float* ffh = ws + 657920;
  float* logits = ws + 1184256;
  float* part = ws + 1249792;

  void* kargs[] = {(void*)&p};
  hipError_t err =
      hipLaunchCooperativeKernel(mega, dim3(GRID_), dim3(256), kargs, 0, stream);
  if (err != hipSuccess) {
    (void)hipGetLastError();  // clear sticky error; use non-coop fallback
    embed_wrap<<<dim3(S_), dim3(256), 0, stream>>>(p.in_x, p.emb_w, p.emb_b,
                                                   p.pos_emb, p.cls_emb, src);
    for (int l = 0; l < 4; ++l) {
      gemm_wrap<true, false, false><<<dim3(120), dim3(256), 0, stream>>>(
          src, p.ipw + (size_t)l * 1536 * 512, p.ipb + l * 1536, qkv, S_, 1536,
          512, 512, 24, 0);
      attn_wrap<<<dim3(S_), dim3(256), 0, stream>>>(qkv, attnO);
      gemm_wrap<true, false, true><<<dim3(320), dim3(256), 0, stream>>>(
          attnO, p.aow + (size_t)l * 512 * 512, nullptr, part, S_, 512, 512,
          64, 8, S_ * D_);
      ln_wrap<<<dim3(S_), dim3(256), 0, stream>>>(part, 8, p.aob + l * 512,
                                                  src, p.ln1g + l * 512,
                                                  p.ln1b + l * 512);
      gemm_wrap<false, true, false><<<dim3(160), dim3(256), 0, stream>>>(
          src, p.fw1 + (size_t)l * 512 * 2048, p.fb1 + l * 2048, ffh, S_, 2048,
          512, 512, 32, 0);
      gemm_wrap<false, false, true><<<dim3(320), dim3(256), 0, stream>>>(
          ffh, p.fw2 + (size_t)l * 2048 * 512, nullptr, part, S_, 512, 2048,
          256, 8, S_ * D_);
      ln_wrap<<<dim3(S_), dim3(256), 0, stream>>>(part, 8, p.fb2 + l * 512,
                                                  src, p.ln2g + l * 512,
                                                  p.ln2b + l * 512);
    }
    gemv_wrap<<<dim3(512), dim3(256), 0, stream>>>(src, p.out_w, part);
    logits_wrap<<<dim3(64), dim3(256), 0, stream>>>(part, p.out_b, logits);
  }
  sinkhorn_kernel<<<dim3(1), dim3(1024), 0, stream>>>(logits, out);
}

// Round 8
// 1734.065 us; speedup vs baseline: 1.3139x; 1.3139x over previous
//
#include <hip/hip_runtime.h>
#include <hip/hip_cooperative_groups.h>
#include <math.h>

namespace cg = cooperative_groups;

#define S_ 257
#define D_ 512
#define MB_ 5  // ceil(257/64)
#define GRID_ 256

struct MegaP {
  const float* in_x;
  const float* emb_w;
  const float* emb_b;
  const float* pos_emb;
  const float* cls_emb;
  const float* ipw;
  const float* ipb;
  const float* aow;
  const float* aob;
  const float* fw1;
  const float* fb1;
  const float* fw2;
  const float* fb2;
  const float* ln1g;
  const float* ln1b;
  const float* ln2g;
  const float* ln2b;
  const float* out_w;
  const float* out_b;
  float* ws;
};

using Tile = float[2][32][68];

// ---- embed row job ---------------------------------------------------------
__device__ __forceinline__ void embed_job(
    int row, const float* __restrict__ in_x, const float* __restrict__ emb_w,
    const float* __restrict__ emb_b, const float* __restrict__ pos_emb,
    const float* __restrict__ cls_emb, float* __restrict__ src,
    float* __restrict__ sbuf) {
  const int tid = threadIdx.x;
  if (row == 0) {
    for (int j = tid; j < D_; j += 256) src[j] = cls_emb[j] + pos_emb[j];
    __syncthreads();
    return;
  }
  if (tid < 64) sbuf[tid] = in_x[(row - 1) * 64 + tid];
  __syncthreads();
  for (int j = tid; j < D_; j += 256) {
    float acc = emb_b[j];
#pragma unroll 8
    for (int k = 0; k < 64; ++k) acc += sbuf[k] * emb_w[k * D_ + j];
    src[row * D_ + j] = acc + pos_emb[row * D_ + j];
  }
  __syncthreads();
}

// ---- proven 64x64 dbuf GEMM datapath as a per-block job --------------------
template <bool TRANSB, bool RELU, bool SPLITK>
__device__ __forceinline__ void gemm_job(
    int job, const float* __restrict__ A, const float* __restrict__ B,
    const float* __restrict__ bias, float* __restrict__ out, int M, int N,
    int K, int kslice, int nb, int MNtot, Tile& As, Tile& Bs) {
  const int tid = threadIdx.x;
  const int by = job % MB_;
  const int t2 = job / MB_;
  const int bx = t2 % nb;
  const int bz = t2 / nb;
  const int m0 = by * 64, n0 = bx * 64, kbeg = bz * kslice;

  const int sm = tid & 63;
  const int sk = (tid >> 6) * 8;
  const int bk = tid >> 3;
  const int bn = (tid & 7) * 8;

  float4 ra0, ra1, rb0, rb1;
  const float4 z4 = make_float4(0.f, 0.f, 0.f, 0.f);

  auto loadT = [&](int k0) {
    const int gm = m0 + sm;
    if (gm < M) {
      const float* p = &A[(size_t)gm * K + k0 + sk];
      ra0 = *reinterpret_cast<const float4*>(p);
      ra1 = *reinterpret_cast<const float4*>(p + 4);
    } else {
      ra0 = z4;
      ra1 = z4;
    }
    if (TRANSB) {
      const float* p = &B[(size_t)(n0 + sm) * K + k0 + sk];
      rb0 = *reinterpret_cast<const float4*>(p);
      rb1 = *reinterpret_cast<const float4*>(p + 4);
    } else {
      const float* p = &B[(size_t)(k0 + bk) * N + n0 + bn];
      rb0 = *reinterpret_cast<const float4*>(p);
      rb1 = *reinterpret_cast<const float4*>(p + 4);
    }
  };
  auto storeT = [&](int b) {
    As[b][sk + 0][sm] = ra0.x;
    As[b][sk + 1][sm] = ra0.y;
    As[b][sk + 2][sm] = ra0.z;
    As[b][sk + 3][sm] = ra0.w;
    As[b][sk + 4][sm] = ra1.x;
    As[b][sk + 5][sm] = ra1.y;
    As[b][sk + 6][sm] = ra1.z;
    As[b][sk + 7][sm] = ra1.w;
    if (TRANSB) {
      Bs[b][sk + 0][sm] = rb0.x;
      Bs[b][sk + 1][sm] = rb0.y;
      Bs[b][sk + 2][sm] = rb0.z;
      Bs[b][sk + 3][sm] = rb0.w;
      Bs[b][sk + 4][sm] = rb1.x;
      Bs[b][sk + 5][sm] = rb1.y;
      Bs[b][sk + 6][sm] = rb1.z;
      Bs[b][sk + 7][sm] = rb1.w;
    } else {
      *reinterpret_cast<float4*>(&Bs[b][bk][bn]) = rb0;
      *reinterpret_cast<float4*>(&Bs[b][bk][bn + 4]) = rb1;
    }
  };

  float acc[4][4] = {};
  const int tx4 = (tid & 15) * 4;
  const int ty4 = (tid >> 4) * 4;

  const int nt = kslice >> 5;
  loadT(kbeg);
  storeT(0);
  __syncthreads();
  int buf = 0;
  for (int t = 0; t < nt; ++t) {
    const bool more = (t + 1 < nt);
    if (more) loadT(kbeg + (t + 1) * 32);
#pragma unroll
    for (int k = 0; k < 32; ++k) {
      const float4 av = *reinterpret_cast<const float4*>(&As[buf][k][ty4]);
      const float4 bv = *reinterpret_cast<const float4*>(&Bs[buf][k][tx4]);
      acc[0][0] += av.x * bv.x;
      acc[0][1] += av.x * bv.y;
      acc[0][2] += av.x * bv.z;
      acc[0][3] += av.x * bv.w;
      acc[1][0] += av.y * bv.x;
      acc[1][1] += av.y * bv.y;
      acc[1][2] += av.y * bv.z;
      acc[1][3] += av.y * bv.w;
      acc[2][0] += av.z * bv.x;
      acc[2][1] += av.z * bv.y;
      acc[2][2] += av.z * bv.z;
      acc[2][3] += av.z * bv.w;
      acc[3][0] += av.w * bv.x;
      acc[3][1] += av.w * bv.y;
      acc[3][2] += av.w * bv.z;
      acc[3][3] += av.w * bv.w;
    }
    if (more) storeT(buf ^ 1);
    __syncthreads();
    buf ^= 1;
  }

  float* pb = SPLITK ? (out + (size_t)bz * MNtot) : out;
#pragma unroll
  for (int i = 0; i < 4; ++i) {
    const int m = m0 + ty4 + i;
    if (m >= M) break;
    const int n = n0 + tx4;
    float4 v = make_float4(acc[i][0], acc[i][1], acc[i][2], acc[i][3]);
    if (!SPLITK) {
      const float4 bb = *reinterpret_cast<const float4*>(&bias[n]);
      v.x += bb.x;
      v.y += bb.y;
      v.z += bb.z;
      v.w += bb.w;
      if (RELU) {
        v.x = fmaxf(v.x, 0.f);
        v.y = fmaxf(v.y, 0.f);
        v.z = fmaxf(v.z, 0.f);
        v.w = fmaxf(v.w, 0.f);
      }
    }
    *reinterpret_cast<float4*>(&pb[(size_t)m * N + n]) = v;
  }
  __syncthreads();
}

// ---- attention job: one query row, 8 head-groups x 32 lanes ----------------
__device__ __forceinline__ void attn_job(int q, const float* __restrict__ qkv,
                                         float* __restrict__ attnO,
                                         float (*sc)[260], float (*qsh)[64]) {
  const int tid = threadIdx.x;
  const int lane = tid & 31;
  const int hg = tid >> 5;
  {
    const int e = tid * 2;
    const float2 v =
        *reinterpret_cast<const float2*>(&qkv[(size_t)q * 1536 + e]);
    qsh[e >> 6][e & 63] = v.x;
    qsh[e >> 6][(e & 63) + 1] = v.y;
  }
  __syncthreads();
  float lm = -1e30f;
  for (int j = lane; j < S_; j += 32) {
    const float4* kr =
        reinterpret_cast<const float4*>(&qkv[(size_t)j * 1536 + 512 + hg * 64]);
    const float4* qr = reinterpret_cast<const float4*>(&qsh[hg][0]);
    float acc = 0.f;
#pragma unroll
    for (int d = 0; d < 16; ++d) {
      const float4 kk = kr[d], qq = qr[d];
      acc += kk.x * qq.x + kk.y * qq.y + kk.z * qq.z + kk.w * qq.w;
    }
    const float s = acc * 0.125f;
    sc[hg][j] = s;
    lm = fmaxf(lm, s);
  }
#pragma unroll
  for (int off = 16; off > 0; off >>= 1)
    lm = fmaxf(lm, __shfl_xor(lm, off, 32));
  float ls = 0.f;
  for (int j = lane; j < S_; j += 32) {
    const float pw = __expf(sc[hg][j] - lm);
    sc[hg][j] = pw;
    ls += pw;
  }
#pragma unroll
  for (int off = 16; off > 0; off >>= 1) ls += __shfl_xor(ls, off, 32);
  const float inv = 1.f / ls;
  __syncthreads();
  float a0 = 0.f, a1 = 0.f;
  for (int j = 0; j < S_; ++j) {
    const float pw = sc[hg][j];
    const float2 vv = *reinterpret_cast<const float2*>(
        &qkv[(size_t)j * 1536 + 1024 + hg * 64 + lane * 2]);
    a0 += pw * vv.x;
    a1 += pw * vv.y;
  }
  *reinterpret_cast<float2*>(&attnO[(size_t)q * D_ + hg * 64 + lane * 2]) =
      make_float2(a0 * inv, a1 * inv);
  __syncthreads();
}

// ---- split-K reduce + bias + residual + LayerNorm row job ------------------
__device__ __forceinline__ void ln_job(int row, const float* __restrict__ part,
                                       int S, const float* __restrict__ bias,
                                       float* __restrict__ io,
                                       const float* __restrict__ g,
                                       const float* __restrict__ b,
                                       float* redA, float* redB) {
  const int tid = threadIdx.x;
  const size_t base = (size_t)row * D_;
  float x0 = io[base + tid] + bias[tid];
  float x1 = io[base + 256 + tid] + bias[256 + tid];
  for (int s = 0; s < S; ++s) {
    x0 += part[(size_t)s * (size_t)(S_ * D_) + base + tid];
    x1 += part[(size_t)s * (size_t)(S_ * D_) + base + 256 + tid];
  }
  float sm = x0 + x1;
#pragma unroll
  for (int off = 32; off > 0; off >>= 1) sm += __shfl_down(sm, off);
  if ((tid & 63) == 0) redA[tid >> 6] = sm;
  __syncthreads();
  const float mu = (redA[0] + redA[1] + redA[2] + redA[3]) * (1.f / 512.f);
  const float d0 = x0 - mu, d1 = x1 - mu;
  float qv = d0 * d0 + d1 * d1;
#pragma unroll
  for (int off = 32; off > 0; off >>= 1) qv += __shfl_down(qv, off);
  if ((tid & 63) == 0) redB[tid >> 6] = qv;
  __syncthreads();
  const float var = (redB[0] + redB[1] + redB[2] + redB[3]) * (1.f / 512.f);
  const float inv = rsqrtf(var + 1e-5f);
  io[base + tid] = d0 * inv * g[tid] + b[tid];
  io[base + 256 + tid] = d1 * inv * g[256 + tid] + b[256 + tid];
  __syncthreads();
}

// ---- head gemv / logits jobs -----------------------------------------------
__device__ __forceinline__ void gemv_job(int job, const float* __restrict__ src,
                                         const float* __restrict__ out_w,
                                         float* __restrict__ part,
                                         float* __restrict__ sbuf) {
  const int tid = threadIdx.x;
  const int jc = job & 63;
  const int dc = job >> 6;
  if (tid < 64) sbuf[tid] = src[dc * 64 + tid];
  __syncthreads();
  const int j0 = jc * 1024 + tid * 4;
  float4 acc = make_float4(0.f, 0.f, 0.f, 0.f);
  for (int d = 0; d < 64; ++d) {
    const float sv = sbuf[d];
    const float4 w = *reinterpret_cast<const float4*>(
        &out_w[(size_t)(dc * 64 + d) * 65536 + j0]);
    acc.x += sv * w.x;
    acc.y += sv * w.y;
    acc.z += sv * w.z;
    acc.w += sv * w.w;
  }
  *reinterpret_cast<float4*>(&part[(size_t)dc * 65536 + j0]) = acc;
  __syncthreads();
}

__device__ __forceinline__ void logits_job(int job,
                                           const float* __restrict__ part,
                                           const float* __restrict__ out_b,
                                           float* __restrict__ logits) {
  const int j = job * 1024 + threadIdx.x * 4;
  float4 acc = *reinterpret_cast<const float4*>(&out_b[j]);
#pragma unroll
  for (int s = 0; s < 8; ++s) {
    const float4 v =
        *reinterpret_cast<const float4*>(&part[(size_t)s * 65536 + j]);
    acc.x += v.x;
    acc.y += v.y;
    acc.z += v.z;
    acc.w += v.w;
  }
  *reinterpret_cast<float4*>(&logits[j]) = acc;
}

// ---- the megakernel --------------------------------------------------------
// (256,1): 256-VGPR budget. Round 7's (256,2)/128-VGPR cap spilled the
// 16-dword prefetch set every k-tile -> 967 MB scratch traffic = the whole
// 2.3 ms. Grid is 256 = 1 block/CU, so the cap change costs no occupancy.
__global__ __launch_bounds__(256, 1) void mega(MegaP p) {
  cg::grid_group grid = cg::this_grid();
  const int bid = blockIdx.x;

  __shared__ __align__(16) float As[2][32][68];
  __shared__ __align__(16) float Bs[2][32][68];
  __shared__ __align__(16) float sc[8][260];
  __shared__ __align__(16) float qsh[8][64];
  __shared__ float redA[4], redB[4];
  __shared__ __align__(16) float sbuf[64];

  float* ws = p.ws;
  float* src = ws;               // 257*512
  float* qkv = ws + 131584;      // 257*1536
  float* attnO = ws + 526336;    // 257*512
  float* ffh = ws + 657920;      // 257*2048
  float* logits = ws + 1184256;  // 65536
  float* part = ws + 1249792;    // 8*131584 (also 8*65536 head partials)

  for (int row = bid; row < S_; row += GRID_)
    embed_job(row, p.in_x, p.emb_w, p.emb_b, p.pos_emb, p.cls_emb, src, sbuf);
  grid.sync();

  for (int l = 0; l < 4; ++l) {
    const float* ipw_l = p.ipw + (size_t)l * 1536 * 512;
    const float* ipb_l = p.ipb + l * 1536;
    const float* aow_l = p.aow + (size_t)l * 512 * 512;
    const float* aob_l = p.aob + l * 512;
    const float* fw1_l = p.fw1 + (size_t)l * 512 * 2048;
    const float* fb1_l = p.fb1 + l * 2048;
    const float* fw2_l = p.fw2 + (size_t)l * 2048 * 512;
    const float* fb2_l = p.fb2 + l * 512;

    for (int job = bid; job < 24 * MB_; job += GRID_)
      gemm_job<true, false, false>(job, src, ipw_l, ipb_l, qkv, S_, 1536, 512,
                                   512, 24, 0, As, Bs);
    grid.sync();

    for (int q = bid; q < S_; q += GRID_) attn_job(q, qkv, attnO, sc, qsh);
    grid.sync();

    for (int job = bid; job < 8 * MB_ * 8; job += GRID_)
      gemm_job<true, false, true>(job, attnO, aow_l, nullptr, part, S_, 512,
                                  512, 64, 8, S_ * D_, As, Bs);
    grid.sync();

    for (int row = bid; row < S_; row += GRID_)
      ln_job(row, part, 8, aob_l, src, p.ln1g + l * 512, p.ln1b + l * 512,
             redA, redB);
    grid.sync();

    for (int job = bid; job < 32 * MB_; job += GRID_)
      gemm_job<false, true, false>(job, src, fw1_l, fb1_l, ffh, S_, 2048, 512,
                                   512, 32, 0, As, Bs);
    grid.sync();

    for (int job = bid; job < 8 * MB_ * 8; job += GRID_)
      gemm_job<false, false, true>(job, ffh, fw2_l, nullptr, part, S_, 512,
                                   2048, 256, 8, S_ * D_, As, Bs);
    grid.sync();

    for (int row = bid; row < S_; row += GRID_)
      ln_job(row, part, 8, fb2_l, src, p.ln2g + l * 512, p.ln2b + l * 512,
             redA, redB);
    grid.sync();
  }

  for (int job = bid; job < 512; job += GRID_)
    gemv_job(job, src, p.out_w, part, sbuf);
  grid.sync();

  for (int job = bid; job < 64; job += GRID_)
    logits_job(job, part, p.out_b, logits);
}

// ---- fallback wrappers (non-cooperative), reuse the same device jobs -------
__global__ __launch_bounds__(256) void embed_wrap(
    const float* in_x, const float* emb_w, const float* emb_b,
    const float* pos_emb, const float* cls_emb, float* src) {
  __shared__ __align__(16) float sbuf[64];
  embed_job(blockIdx.x, in_x, emb_w, emb_b, pos_emb, cls_emb, src, sbuf);
}

template <bool TRANSB, bool RELU, bool SPLITK>
__global__ __launch_bounds__(256, 2) void gemm_wrap(const float* A,
                                                    const float* B,
                                                    const float* bias,
                                                    float* out, int M, int N,
                                                    int K, int kslice, int nb,
                                                    int MNtot) {
  __shared__ __align__(16) float As[2][32][68];
  __shared__ __align__(16) float Bs[2][32][68];
  gemm_job<TRANSB, RELU, SPLITK>(blockIdx.x, A, B, bias, out, M, N, K, kslice,
                                 nb, MNtot, As, Bs);
}

__global__ __launch_bounds__(256) void attn_wrap(const float* qkv,
                                                 float* attnO) {
  __shared__ __align__(16) float sc[8][260];
  __shared__ __align__(16) float qsh[8][64];
  attn_job(blockIdx.x, qkv, attnO, sc, qsh);
}

__global__ __launch_bounds__(256) void ln_wrap(const float* part, int S,
                                               const float* bias, float* io,
                                               const float* g, const float* b) {
  __shared__ float redA[4], redB[4];
  ln_job(blockIdx.x, part, S, bias, io, g, b, redA, redB);
}

__global__ __launch_bounds__(256) void gemv_wrap(const float* src,
                                                 const float* out_w,
                                                 float* part) {
  __shared__ __align__(16) float sbuf[64];
  gemv_job(blockIdx.x, src, out_w, part, sbuf);
}

__global__ __launch_bounds__(256) void logits_wrap(const float* part,
                                                   const float* out_b,
                                                   float* logits) {
  logits_job(blockIdx.x, part, out_b, logits);
}

// ---------------- sinkhorn (rank-1 reformulation, unchanged) ----------------
__global__ __launch_bounds__(1024) void sinkhorn_kernel(
    const float* __restrict__ logits, float* __restrict__ out) {
  const int tid = threadIdx.x;
  const int tx = tid & 31;
  const int ty = tid >> 5;
  const int i0 = ty * 8, j0 = tx * 8;
  float E[8][8];
#pragma unroll
  for (int ii = 0; ii < 8; ++ii) {
    const float4 a =
        *reinterpret_cast<const float4*>(&logits[(i0 + ii) * 256 + j0]);
    const float4 b =
        *reinterpret_cast<const float4*>(&logits[(i0 + ii) * 256 + j0 + 4]);
    E[ii][0] = __expf(a.x);
    E[ii][1] = __expf(a.y);
    E[ii][2] = __expf(a.z);
    E[ii][3] = __expf(a.w);
    E[ii][4] = __expf(b.x);
    E[ii][5] = __expf(b.y);
    E[ii][6] = __expf(b.z);
    E[ii][7] = __expf(b.w);
  }
  __shared__ float part[32][8][32];
  __shared__ int partI[32][8][32];
  __shared__ float uu[256];
  __shared__ float vv[256];
  __shared__ int amax[256];
  if (tid < 256) uu[tid] = 1.f;
  __syncthreads();
  for (int it = 0; it < 20; ++it) {
    float ul[8];
#pragma unroll
    for (int ii = 0; ii < 8; ++ii) ul[ii] = uu[i0 + ii];
#pragma unroll
    for (int jj = 0; jj < 8; ++jj) {
      float s = 0.f;
#pragma unroll
      for (int ii = 0; ii < 8; ++ii) s += E[ii][jj] * ul[ii];
      part[ty][jj][tx] = s;
    }
    __syncthreads();
    if (tid < 256) {
      const int jj = tid >> 5, txr = tid & 31;
      float s = 0.f;
#pragma unroll
      for (int p = 0; p < 32; ++p) s += part[p][jj][txr];
      vv[txr * 8 + jj] = 1.f / s;
    }
    __syncthreads();
    float vl[8];
#pragma unroll
    for (int jj = 0; jj < 8; ++jj) vl[jj] = vv[j0 + jj];
#pragma unroll
    for (int ii = 0; ii < 8; ++ii) {
      float s = 0.f;
#pragma unroll
      for (int jj = 0; jj < 8; ++jj) s += E[ii][jj] * vl[jj];
      part[ty][ii][tx] = s;
    }
    __syncthreads();
    if (tid < 256) {
      const int i = tid;
      float s = 0.f;
#pragma unroll
      for (int p = 0; p < 32; ++p) {
        const int pr = (p + i) & 31;
        s += part[i >> 3][i & 7][pr];
      }
      uu[i] = 1.f / s;
    }
    __syncthreads();
  }
  float ul[8], vl[8];
#pragma unroll
  for (int ii = 0; ii < 8; ++ii) ul[ii] = uu[i0 + ii];
#pragma unroll
  for (int jj = 0; jj < 8; ++jj) vl[jj] = vv[j0 + jj];
#pragma unroll
  for (int ii = 0; ii < 8; ++ii) {
    float vals[8];
    float best = -1.f;
    int bidx = 0;
#pragma unroll
    for (int jj = 0; jj < 8; ++jj) {
      const float p = E[ii][jj] * ul[ii] * vl[jj];
      vals[jj] = p;
      if (p > best) {
        best = p;
        bidx = j0 + jj;
      }
    }
    *reinterpret_cast<float4*>(&out[(i0 + ii) * 256 + j0]) =
        make_float4(vals[0], vals[1], vals[2], vals[3]);
    *reinterpret_cast<float4*>(&out[(i0 + ii) * 256 + j0 + 4]) =
        make_float4(vals[4], vals[5], vals[6], vals[7]);
    part[ty][ii][tx] = best;
    partI[ty][ii][tx] = bidx;
  }
  __syncthreads();
  if (tid < 256) {
    const int i = tid;
    float best = -1.f;
    int bidx = 1 << 30;
#pragma unroll
    for (int p = 0; p < 32; ++p) {
      const int pr = (p + i) & 31;
      const float v = part[i >> 3][i & 7][pr];
      const int ix = partI[i >> 3][i & 7][pr];
      if (v > best || (v == best && ix < bidx)) {
        best = v;
        bidx = ix;
      }
    }
    amax[i] = bidx;
  }
  __syncthreads();
#pragma unroll
  for (int ii = 0; ii < 8; ++ii) {
    const int am = amax[i0 + ii];
    float4 h0, h1;
    h0.x = (j0 + 0 == am) ? 1.f : 0.f;
    h0.y = (j0 + 1 == am) ? 1.f : 0.f;
    h0.z = (j0 + 2 == am) ? 1.f : 0.f;
    h0.w = (j0 + 3 == am) ? 1.f : 0.f;
    h1.x = (j0 + 4 == am) ? 1.f : 0.f;
    h1.y = (j0 + 5 == am) ? 1.f : 0.f;
    h1.z = (j0 + 6 == am) ? 1.f : 0.f;
    h1.w = (j0 + 7 == am) ? 1.f : 0.f;
    *reinterpret_cast<float4*>(&out[65536 + (i0 + ii) * 256 + j0]) = h0;
    *reinterpret_cast<float4*>(&out[65536 + (i0 + ii) * 256 + j0 + 4]) = h1;
  }
}

// ---------------- host-side launch ------------------------------------------
extern "C" void kernel_launch(void* const* d_in, const int* in_sizes, int n_in,
                              void* d_out, int out_size, void* d_ws,
                              size_t ws_size, hipStream_t stream) {
  (void)in_sizes;
  (void)n_in;
  (void)out_size;
  (void)ws_size;
  MegaP p;
  p.in_x = (const float*)d_in[0];
  p.emb_w = (const float*)d_in[1];
  p.emb_b = (const float*)d_in[2];
  p.pos_emb = (const float*)d_in[3];
  p.cls_emb = (const float*)d_in[4];
  p.ipw = (const float*)d_in[5];
  p.ipb = (const float*)d_in[6];
  p.aow = (const float*)d_in[7];
  p.aob = (const float*)d_in[8];
  p.fw1 = (const float*)d_in[9];
  p.fb1 = (const float*)d_in[10];
  p.fw2 = (const float*)d_in[11];
  p.fb2 = (const float*)d_in[12];
  p.ln1g = (const float*)d_in[13];
  p.ln1b = (const float*)d_in[14];
  p.ln2g = (const float*)d_in[15];
  p.ln2b = (const float*)d_in[16];
  p.out_w = (const float*)d_in[17];
  p.out_b = (const float*)d_in[18];
  p.ws = (float*)d_ws;
  float* out = (float*)d_out;
  float* ws = p.ws;
  float* src = ws;
  float* qkv = ws + 131584;
  float* attnO = ws + 526336;
  float* ffh = ws + 657920;
  float* logits = ws + 1184256;
  float* part = ws + 1249792;

  void* kargs[] = {(void*)&p};
  hipError_t err =
      hipLaunchCooperativeKernel(mega, dim3(GRID_), dim3(256), kargs, 0, stream);
  if (err != hipSuccess) {
    (void)hipGetLastError();  // clear sticky error; use non-coop fallback
    embed_wrap<<<dim3(S_), dim3(256), 0, stream>>>(p.in_x, p.emb_w, p.emb_b,
                                                   p.pos_emb, p.cls_emb, src);
    for (int l = 0; l < 4; ++l) {
      gemm_wrap<true, false, false><<<dim3(120), dim3(256), 0, stream>>>(
          src, p.ipw + (size_t)l * 1536 * 512, p.ipb + l * 1536, qkv, S_, 1536,
          512, 512, 24, 0);
      attn_wrap<<<dim3(S_), dim3(256), 0, stream>>>(qkv, attnO);
      gemm_wrap<true, false, true><<<dim3(320), dim3(256), 0, stream>>>(
          attnO, p.aow + (size_t)l * 512 * 512, nullptr, part, S_, 512, 512,
          64, 8, S_ * D_);
      ln_wrap<<<dim3(S_), dim3(256), 0, stream>>>(part, 8, p.aob + l * 512,
                                                  src, p.ln1g + l * 512,
                                                  p.ln1b + l * 512);
      gemm_wrap<false, true, false><<<dim3(160), dim3(256), 0, stream>>>(
          src, p.fw1 + (size_t)l * 512 * 2048, p.fb1 + l * 2048, ffh, S_, 2048,
          512, 512, 32, 0);
      gemm_wrap<false, false, true><<<dim3(320), dim3(256), 0, stream>>>(
          ffh, p.fw2 + (size_t)l * 2048 * 512, nullptr, part, S_, 512, 2048,
          256, 8, S_ * D_);
      ln_wrap<<<dim3(S_), dim3(256), 0, stream>>>(part, 8, p.fb2 + l * 512,
                                                  src, p.ln2g + l * 512,
                                                  p.ln2b + l * 512);
    }
    gemv_wrap<<<dim3(512), dim3(256), 0, stream>>>(src, p.out_w, part);
    logits_wrap<<<dim3(64), dim3(256), 0, stream>>>(part, p.out_b, logits);
  }
  sinkhorn_kernel<<<dim3(1), dim3(1024), 0, stream>>>(logits, out);
}